// Round 2
// baseline (607.495 us; speedup 1.0000x reference)
//
#include <hip/hip_runtime.h>

// ---- problem constants ----
#define B_    2
#define N_    2049
#define NPAD  2112          // N padded to multiple of 64
#define D_    1024
#define H_    16
#define DH    64
#define MROWS (B_ * N_)     // 4098
#define MPAD  4160          // MROWS padded to multiple of 64

using bf16x8 = __attribute__((ext_vector_type(8))) short;
using f32x4  = __attribute__((ext_vector_type(4))) float;

__device__ __forceinline__ float bf2f(short s) {
  union { unsigned u; float f; } a; a.u = ((unsigned)(unsigned short)s) << 16; return a.f;
}
__device__ __forceinline__ short f2bf(float f) {
  union { float f; unsigned u; } a; a.f = f;
  unsigned r = a.u + 0x7fffu + ((a.u >> 16) & 1u);   // round-to-nearest-even
  return (short)(r >> 16);
}

// ---------------- LayerNorm: fp32 in -> bf16 out ----------------
__global__ __launch_bounds__(256) void ln_kernel(const float* __restrict__ x,
                                                 const float* __restrict__ gamma,
                                                 const float* __restrict__ beta,
                                                 short* __restrict__ xn) {
  int row = blockIdx.x;                       // 0..4097
  int tid = threadIdx.x;                      // 256 threads, 4 floats each
  const float4 v = ((const float4*)(x + (size_t)row * D_))[tid];
  float s  = v.x + v.y + v.z + v.w;
  float ss = v.x * v.x + v.y * v.y + v.z * v.z + v.w * v.w;
  for (int o = 1; o < 64; o <<= 1) { s += __shfl_xor(s, o, 64); ss += __shfl_xor(ss, o, 64); }
  __shared__ float sb[4], s2b[4];
  int wid = tid >> 6;
  if ((tid & 63) == 0) { sb[wid] = s; s2b[wid] = ss; }
  __syncthreads();
  float st  = sb[0] + sb[1] + sb[2] + sb[3];
  float sst = s2b[0] + s2b[1] + s2b[2] + s2b[3];
  float mu  = st * (1.0f / D_);
  float var = sst * (1.0f / D_) - mu * mu;
  float rs  = rsqrtf(var + 1e-5f);
  const float4 g  = ((const float4*)gamma)[tid];
  const float4 be = ((const float4*)beta)[tid];
  short4 o4;
  o4.x = f2bf((v.x - mu) * rs * g.x + be.x);
  o4.y = f2bf((v.y - mu) * rs * g.y + be.y);
  o4.z = f2bf((v.z - mu) * rs * g.z + be.z);
  o4.w = f2bf((v.w - mu) * rs * g.w + be.w);
  ((short4*)(xn + (size_t)row * D_))[tid] = o4;
}

// ------------- transpose+cast: fp32 [K][Nn] -> bf16 [Nn][K] -------------
__global__ __launch_bounds__(256) void transpose_cast(const float* __restrict__ in,
                                                      short* __restrict__ out,
                                                      int K, int Nn) {
  int idx = blockIdx.x * 256 + threadIdx.x;
  if (idx >= K * Nn) return;
  int kk = idx / Nn, nn = idx - kk * Nn;
  out[(size_t)nn * K + kk] = f2bf(in[idx]);
}

// ------------- bf16 MFMA GEMM: C[M][Ncols] = A[M][K] * BT[Ncols][K]^T -------------
// workgroup = 4 waves (2x2), wave tile 32x32, block tile 64x64
// OutT = unsigned short (bf16 store) or float (fp32 store)
template <typename OutT>
__global__ __launch_bounds__(256) void gemm_bf16(const short* __restrict__ A,
                                                 const short* __restrict__ BT,
                                                 OutT* __restrict__ C,
                                                 int Mstore, int Ncols, int K) {
  int lane = threadIdx.x & 63, wid = threadIdx.x >> 6;
  int quad = lane >> 4, l16 = lane & 15;
  int m0 = blockIdx.x * 64 + (wid >> 1) * 32;
  int n0 = blockIdx.y * 64 + (wid & 1) * 32;
  f32x4 acc[2][2] = {};
  const short* Ap0 = A + (size_t)(m0 + l16) * K + quad * 8;
  const short* Ap1 = Ap0 + (size_t)16 * K;
  const short* Bp0 = BT + (size_t)(n0 + l16) * K + quad * 8;
  const short* Bp1 = Bp0 + (size_t)16 * K;
  for (int kk = 0; kk < K; kk += 32) {
    bf16x8 a0 = *(const bf16x8*)(Ap0 + kk);
    bf16x8 a1 = *(const bf16x8*)(Ap1 + kk);
    bf16x8 b0 = *(const bf16x8*)(Bp0 + kk);
    bf16x8 b1 = *(const bf16x8*)(Bp1 + kk);
    acc[0][0] = __builtin_amdgcn_mfma_f32_16x16x32_bf16(a0, b0, acc[0][0], 0, 0, 0);
    acc[0][1] = __builtin_amdgcn_mfma_f32_16x16x32_bf16(a0, b1, acc[0][1], 0, 0, 0);
    acc[1][0] = __builtin_amdgcn_mfma_f32_16x16x32_bf16(a1, b0, acc[1][0], 0, 0, 0);
    acc[1][1] = __builtin_amdgcn_mfma_f32_16x16x32_bf16(a1, b1, acc[1][1], 0, 0, 0);
  }
  #pragma unroll
  for (int im = 0; im < 2; ++im)
    #pragma unroll
    for (int in_ = 0; in_ < 2; ++in_)
      #pragma unroll
      for (int r = 0; r < 4; ++r) {
        int row = m0 + im * 16 + quad * 4 + r;     // C/D: row = quad*4+reg
        if (row < Mstore) {
          int col = n0 + in_ * 16 + l16;           // C/D: col = lane&15
          float val = acc[im][in_][r];
          if constexpr (sizeof(OutT) == 2)
            C[(size_t)row * Ncols + col] = (OutT)(unsigned short)f2bf(val);
          else
            C[(size_t)row * Ncols + col] = (OutT)val;
        }
      }
}

// ------------- RoPE + head reshape: qkv[4160][3072] -> q,k,v [B][H][NPAD][64] -------------
__global__ __launch_bounds__(256) void rope_kernel(const short* __restrict__ qkv,
                                                   short* __restrict__ qg,
                                                   short* __restrict__ kg,
                                                   short* __restrict__ vg) {
  int idx = blockIdx.x * 256 + threadIdx.x;
  const int total = B_ * H_ * NPAD * 32;
  if (idx >= total) return;
  int i = idx & 31;            // rotation pair index 0..31
  int t = idx >> 5;
  int n = t % NPAD; t /= NPAD;
  int h = t & (H_ - 1); int b = t >> 4;
  size_t ob = (((size_t)(b * H_ + h)) * NPAD + n) * DH;
  if (n >= N_) {               // zero-fill padding rows
    qg[ob + i] = 0; qg[ob + i + 32] = 0;
    kg[ob + i] = 0; kg[ob + i + 32] = 0;
    vg[ob + i] = 0; vg[ob + i + 32] = 0;
    return;
  }
  size_t ib = ((size_t)(b * N_ + n)) * 3072 + h * DH;
  float q1 = bf2f(qkv[ib + i]),        q2 = bf2f(qkv[ib + i + 32]);
  float k1 = bf2f(qkv[ib + 1024 + i]), k2 = bf2f(qkv[ib + 1024 + i + 32]);
  float v1 = bf2f(qkv[ib + 2048 + i]), v2 = bf2f(qkv[ib + 2048 + i + 32]);
  if (n > 0) {                 // cls token (n==0) excluded from RoPE
    // accurate libm: inv_freq rel-err must be ~1e-7 (angle up to 2048 rad)
    float ang = (float)(n - 1) * powf(10000.0f, -(float)i * (1.0f / 32.0f));
    float sn, cs; sincosf(ang, &sn, &cs);
    float nq1 = q1 * cs - q2 * sn, nq2 = q2 * cs + q1 * sn;
    float nk1 = k1 * cs - k2 * sn, nk2 = k2 * cs + k1 * sn;
    q1 = nq1; q2 = nq2; k1 = nk1; k2 = nk2;
  }
  qg[ob + i] = f2bf(q1 * 0.125f); qg[ob + i + 32] = f2bf(q2 * 0.125f);  // fold SCALE into q
  kg[ob + i] = f2bf(k1); kg[ob + i + 32] = f2bf(k2);
  vg[ob + i] = f2bf(v1); vg[ob + i + 32] = f2bf(v2);
}

// ------------- flash attention: one workgroup per (b,h, 64-query block) -------------
// 4 waves; wave w owns query rows qblk*64 + w*16 .. +15. Online softmax, K/V tiles of 64.
__global__ __launch_bounds__(256) void attn_kernel(const short* __restrict__ qg,
                                                   const short* __restrict__ kg,
                                                   const short* __restrict__ vg,
                                                   short* __restrict__ attn_out) {
  int bh = blockIdx.y;              // 0..31
  int b = bh >> 4, h = bh & 15;
  int qblk = blockIdx.x;            // 0..32
  int lane = threadIdx.x & 63, wid = threadIdx.x >> 6;
  int quad = lane >> 4, l16 = lane & 15;
  __shared__ short VT[64][64];      // V^T tile: VT[dh][key]
  __shared__ short P[4][16][64];    // per-wave P tile [qrow][key]
  size_t hb = (size_t)bh * NPAD * DH;
  int qrow = qblk * 64 + wid * 16 + l16;         // < 2112
  const short* qp = qg + hb + (size_t)qrow * DH;
  bf16x8 aq0 = *(const bf16x8*)(qp + quad * 8);          // A-frag k=0..31
  bf16x8 aq1 = *(const bf16x8*)(qp + 32 + quad * 8);     // A-frag k=32..63
  f32x4 o[4] = {};
  float mrun[4], lrun[4];
  #pragma unroll
  for (int r = 0; r < 4; ++r) { mrun[r] = -1e30f; lrun[r] = 0.0f; }

  for (int kt = 0; kt < NPAD / 64; ++kt) {       // 33 key tiles
    int k0 = kt * 64;
    __syncthreads();                             // protect prev-iter LDS reads
    {
      // cooperatively stage V^T: 256 threads, 16 elems each
      int row = threadIdx.x >> 2, c8 = (threadIdx.x & 3) * 16;
      const short* vp = vg + hb + (size_t)(k0 + row) * DH + c8;
      bf16x8 v0 = *(const bf16x8*)(vp);
      bf16x8 v1 = *(const bf16x8*)(vp + 8);
      #pragma unroll
      for (int j = 0; j < 8; ++j) { VT[c8 + j][row] = v0[j]; VT[c8 + 8 + j][row] = v1[j]; }
    }
    __syncthreads();

    // S = Q * K^T (scale pre-folded into q)
    f32x4 s[4] = {};
    #pragma unroll
    for (int t = 0; t < 4; ++t) {
      const short* kp = kg + hb + (size_t)(k0 + t * 16 + l16) * DH + quad * 8;
      bf16x8 bk0 = *(const bf16x8*)kp;
      bf16x8 bk1 = *(const bf16x8*)(kp + 32);
      s[t] = __builtin_amdgcn_mfma_f32_16x16x32_bf16(aq0, bk0, s[t], 0, 0, 0);
      s[t] = __builtin_amdgcn_mfma_f32_16x16x32_bf16(aq1, bk1, s[t], 0, 0, 0);
    }
    // mask invalid keys
    #pragma unroll
    for (int t = 0; t < 4; ++t) {
      int col = k0 + t * 16 + l16;
      if (col >= N_) { s[t][0] = -1e30f; s[t][1] = -1e30f; s[t][2] = -1e30f; s[t][3] = -1e30f; }
    }
    // row max (4 regs = 4 query rows per lane-quad; cols spread over 16 lanes)
    f32x4 vmax = s[0];
    #pragma unroll
    for (int t = 1; t < 4; ++t)
      #pragma unroll
      for (int r = 0; r < 4; ++r) vmax[r] = fmaxf(vmax[r], s[t][r]);
    #pragma unroll
    for (int off = 1; off < 16; off <<= 1)
      #pragma unroll
      for (int r = 0; r < 4; ++r) vmax[r] = fmaxf(vmax[r], __shfl_xor(vmax[r], off, 64));
    float mnew[4], alpha[4];
    #pragma unroll
    for (int r = 0; r < 4; ++r) {
      mnew[r] = fmaxf(mrun[r], vmax[r]);
      alpha[r] = __expf(mrun[r] - mnew[r]);
      mrun[r] = mnew[r];
    }
    f32x4 vsum = {};
    #pragma unroll
    for (int t = 0; t < 4; ++t)
      #pragma unroll
      for (int r = 0; r < 4; ++r) {
        float p = __expf(s[t][r] - mnew[r]);
        s[t][r] = p;
        vsum[r] += p;
      }
    #pragma unroll
    for (int off = 1; off < 16; off <<= 1)
      #pragma unroll
      for (int r = 0; r < 4; ++r) vsum[r] += __shfl_xor(vsum[r], off, 64);
    #pragma unroll
    for (int r = 0; r < 4; ++r) lrun[r] = lrun[r] * alpha[r] + vsum[r];
    #pragma unroll
    for (int t = 0; t < 4; ++t)
      #pragma unroll
      for (int r = 0; r < 4; ++r) o[t][r] *= alpha[r];

    // P: C-layout -> LDS -> A-layout (verified m120 pattern)
    #pragma unroll
    for (int t = 0; t < 4; ++t)
      #pragma unroll
      for (int r = 0; r < 4; ++r) P[wid][quad * 4 + r][t * 16 + l16] = f2bf(s[t][r]);
    __syncthreads();
    bf16x8 pa0 = *(const bf16x8*)&P[wid][l16][quad * 8];
    bf16x8 pa1 = *(const bf16x8*)&P[wid][l16][32 + quad * 8];
    #pragma unroll
    for (int t = 0; t < 4; ++t) {
      bf16x8 bv0 = *(const bf16x8*)&VT[t * 16 + l16][quad * 8];
      bf16x8 bv1 = *(const bf16x8*)&VT[t * 16 + l16][32 + quad * 8];
      o[t] = __builtin_amdgcn_mfma_f32_16x16x32_bf16(pa0, bv0, o[t], 0, 0, 0);
      o[t] = __builtin_amdgcn_mfma_f32_16x16x32_bf16(pa1, bv1, o[t], 0, 0, 0);
    }
  }

  // epilogue: O / l, write to attn_out [B*N][1024] at col h*64+dh
  #pragma unroll
  for (int r = 0; r < 4; ++r) {
    float inv = 1.0f / lrun[r];
    int qgl = qblk * 64 + wid * 16 + quad * 4 + r;
    if (qgl < N_) {
      size_t rowb = (size_t)(b * N_ + qgl) * (H_ * DH) + h * DH;
      #pragma unroll
      for (int t = 0; t < 4; ++t)
        attn_out[rowb + t * 16 + l16] = f2bf(o[t][r] * inv);
    }
  }
}

// ---------------- launcher ----------------
extern "C" void kernel_launch(void* const* d_in, const int* in_sizes, int n_in,
                              void* d_out, int out_size, void* d_ws, size_t ws_size,
                              hipStream_t stream) {
  const float* x     = (const float*)d_in[0];
  const float* gamma = (const float*)d_in[1];
  const float* beta  = (const float*)d_in[2];
  const float* w_qkv = (const float*)d_in[3];
  const float* w_out = (const float*)d_in[4];

  // workspace layout (bf16 = short), total ~68.4 MB
  short* wqkvT = (short*)d_ws;                         // [3072][1024]
  short* woutT = wqkvT + (size_t)3072 * 1024;          // [1024][1024]
  short* xn    = woutT + (size_t)1024 * 1024;          // [4160][1024]  (later aliased as attn_out)
  short* qkv   = xn    + (size_t)MPAD * 1024;          // [4160][3072]
  short* qg    = qkv   + (size_t)MPAD * 3072;          // [2][16][2112][64]
  short* kg    = qg    + (size_t)B_ * H_ * NPAD * DH;
  short* vg    = kg    + (size_t)B_ * H_ * NPAD * DH;
  short* attn_out = xn;                                // alias: xn dead after QKV GEMM

  // 1. LayerNorm
  ln_kernel<<<MROWS, 256, 0, stream>>>(x, gamma, beta, xn);
  // 2. weight transposes (fp32 -> bf16, n-major for B-fragments)
  transpose_cast<<<(1024 * 3072 + 255) / 256, 256, 0, stream>>>(w_qkv, wqkvT, 1024, 3072);
  transpose_cast<<<(1024 * 1024 + 255) / 256, 256, 0, stream>>>(w_out, woutT, 1024, 1024);
  // 3. QKV projection (bf16 out)
  {
    dim3 g(MPAD / 64, 3072 / 64);
    gemm_bf16<unsigned short><<<g, 256, 0, stream>>>(xn, wqkvT, (unsigned short*)qkv, MROWS, 3072, 1024);
  }
  // 4. RoPE + reshape to heads (zero-fills NPAD padding)
  rope_kernel<<<(B_ * H_ * NPAD * 32 + 255) / 256, 256, 0, stream>>>(qkv, qg, kg, vg);
  // 5. flash attention (bf16 out to workspace)
  {
    dim3 g(NPAD / 64, B_ * H_);
    attn_kernel<<<g, 256, 0, stream>>>(qg, kg, vg, attn_out);
  }
  // 6. output projection -> d_out (fp32! reference output dtype is float32)
  {
    dim3 g(MPAD / 64, 1024 / 64);
    gemm_bf16<float><<<g, 256, 0, stream>>>(attn_out, woutT, (float*)d_out, MROWS, 1024, 1024);
  }
}